// Round 8
// baseline (252.130 us; speedup 1.0000x reference)
//
#include <hip/hip_runtime.h>
#include <cstdint>
#include <cstddef>

#define DEVI __device__ __forceinline__

typedef short bf16x8 __attribute__((ext_vector_type(8)));
typedef short bf16x4 __attribute__((ext_vector_type(4)));
typedef float f32x4 __attribute__((ext_vector_type(4)));
typedef float f32x16 __attribute__((ext_vector_type(16)));
typedef unsigned short u16x4 __attribute__((ext_vector_type(4)));

constexpr int D_MODEL = 1024;
constexpr int HEADS = 16;
constexpr int DH = 64;
constexpr int SEQ = 2048;
constexpr int KDIM = 1024;

DEVI unsigned short f2bf(float f) {
  union { float f; unsigned u; } v; v.f = f;
  unsigned r = v.u + 0x7fffu + ((v.u >> 16) & 1u);
  return (unsigned short)(r >> 16);
}

// pack two fp32 -> two TRUNCATED bf16 in one dword (a = low16, b = high16)
DEVI unsigned pkbf(float a, float b) {
  return __builtin_amdgcn_perm(__float_as_uint(b), __float_as_uint(a), 0x07060302u);
}

DEVI void cp16(const void* g, void* l) {
  __builtin_amdgcn_global_load_lds(
      (const __attribute__((address_space(1))) void*)g,
      (__attribute__((address_space(3))) void*)l, 16, 0, 0);
}

#define BAR()        asm volatile("s_barrier" ::: "memory")
#define WAITVM(n)    asm volatile("s_waitcnt vmcnt(" #n ")" ::: "memory")
#define WAITLG()     asm volatile("s_waitcnt lgkmcnt(0)" ::: "memory")

// ---------------- fp32 -> bf16 cast, WEIGHTS ONLY (q/k/v cast fused into qkv_gemm) --
__global__ void __launch_bounds__(256) castall(
    const float* __restrict__ Wq, const float* __restrict__ Wk,
    const float* __restrict__ Wv, const float* __restrict__ Wo,
    unsigned short* __restrict__ Wqb, unsigned short* __restrict__ Wkb,
    unsigned short* __restrict__ Wvb, unsigned short* __restrict__ Wob) {
  int bid = blockIdx.x;
  int w = bid >> 10, off = bid & 1023;
  const float* s = (w == 0) ? Wq : ((w == 1) ? Wk : ((w == 2) ? Wv : Wo));
  unsigned short* d = (w == 0) ? Wqb : ((w == 1) ? Wkb : ((w == 2) ? Wvb : Wob));
  int i = (off * 256 + threadIdx.x) * 4;
  float4 x = *(const float4*)(s + i);
  u16x4 o; o[0] = f2bf(x.x); o[1] = f2bf(x.y); o[2] = f2bf(x.z); o[3] = f2bf(x.w);
  *(u16x4*)(d + i) = o;
}

// ---------------- QKV projection with FUSED A-cast (f32 source), 128x128 tile ------
// A (q/k/v) is read directly in f32; each thread loads the same 8+8 elements it
// previously cp16'd, converts with the IDENTICAL f2bf rounding castall used, and
// ds_write_b128's to the IDENTICAL LDS slot -> the staged LDS image is bit-for-bit
// the one the verified kernel consumed.  W still stages via global_load_lds.
// Cadence: robust 2-stage total-drain (round-4-attn pattern): issue A-loads +
// W-cp16 for k+1, COMPUTE(k) while they fly, vmcnt(0), ds_write A, lgkmcnt(0)+BAR.
// No counted vmcnt (round-3 lesson: reg-staged loads in the window break counts).
__global__ void __launch_bounds__(256) qkv_gemm(
    const float* __restrict__ qf, const float* __restrict__ kf,
    const float* __restrict__ vf,
    const unsigned short* __restrict__ Wqb, const unsigned short* __restrict__ Wkb,
    const unsigned short* __restrict__ Wvb,
    const float* __restrict__ bq, const float* __restrict__ bk, const float* __restrict__ bv,
    unsigned short* __restrict__ Qh, unsigned short* __restrict__ Kh,
    unsigned short* __restrict__ Vt, float qscale) {
  __shared__ unsigned short As[2][128 * 32];
  __shared__ unsigned short Bs[2][128 * 32];
  const int bid = blockIdx.x, seg = bid >> 8, inner = bid & 255;
  const int bm = inner & 31, bn = inner >> 5;          // XCD-local swizzle
  const float* A = (seg == 0) ? qf : ((seg == 1) ? kf : vf);
  const unsigned short* W = (seg == 0) ? Wqb : ((seg == 1) ? Wkb : Wvb);
  const float* bias = (seg == 0) ? bq : ((seg == 1) ? bk : bv);
  unsigned short* O = (seg == 0) ? Qh : ((seg == 1) ? Kh : Vt);
  const float oscale = (seg == 0) ? qscale : 1.0f;
  const int mode = (seg == 2) ? 1 : 0;

  const int tid = threadIdx.x, lane = tid & 63, wave = tid >> 6;
  const int l16 = lane & 15, quad = lane >> 4;
  const int wm = (wave >> 1) * 64, wn = (wave & 1) * 64;
  const int sw = (l16 >> 1) & 3;
  f32x4 acc[4][4] = {};

  const int r0 = tid >> 2, p0 = tid & 3;
  const int c0 = (p0 ^ ((r0 >> 1) & 3)) * 8;
  const int r1 = (256 + tid) >> 2;
  const int c1 = (p0 ^ ((r1 >> 1) & 3)) * 8;
  const float* Arow0 = A + (size_t)(bm * 128 + r0) * KDIM + c0;
  const float* Arow1 = A + (size_t)(bm * 128 + r1) * KDIM + c1;
  const unsigned short* Wrow0 = W + (size_t)(bn * 128 + r0) * KDIM + c0;
  const unsigned short* Wrow1 = W + (size_t)(bn * 128 + r1) * KDIM + c1;

  float4 ra0, ra1, rb0, rb1;   // in-flight A (16 f32): r0-block and r1-block

#define ALOAD(K0)                                            \
  do {                                                       \
    ra0 = *(const float4*)(Arow0 + (K0));                    \
    ra1 = *(const float4*)(Arow0 + (K0) + 4);                \
    rb0 = *(const float4*)(Arow1 + (K0));                    \
    rb1 = *(const float4*)(Arow1 + (K0) + 4);                \
  } while (0)

#define ISSUEW(K0, P)                                        \
  do {                                                       \
    cp16(Wrow0 + (K0), &Bs[P][tid * 8]);                     \
    cp16(Wrow1 + (K0), &Bs[P][(256 + tid) * 8]);             \
  } while (0)

#define AWRITE(P)                                            \
  do {                                                       \
    union { u16x4 h[2]; bf16x8 v8; } ua, ub;                 \
    ua.h[0][0] = f2bf(ra0.x); ua.h[0][1] = f2bf(ra0.y);      \
    ua.h[0][2] = f2bf(ra0.z); ua.h[0][3] = f2bf(ra0.w);      \
    ua.h[1][0] = f2bf(ra1.x); ua.h[1][1] = f2bf(ra1.y);      \
    ua.h[1][2] = f2bf(ra1.z); ua.h[1][3] = f2bf(ra1.w);      \
    ub.h[0][0] = f2bf(rb0.x); ub.h[0][1] = f2bf(rb0.y);      \
    ub.h[0][2] = f2bf(rb0.z); ub.h[0][3] = f2bf(rb0.w);      \
    ub.h[1][0] = f2bf(rb1.x); ub.h[1][1] = f2bf(rb1.y);      \
    ub.h[1][2] = f2bf(rb1.z); ub.h[1][3] = f2bf(rb1.w);      \
    *(bf16x8*)&As[P][tid * 8] = ua.v8;                       \
    *(bf16x8*)&As[P][(256 + tid) * 8] = ub.v8;               \
  } while (0)

#define QKV_COMPUTE(P)                                                             \
  do {                                                                             \
    bf16x8 af[4], bfr[4];                                                          \
    _Pragma("unroll") for (int t = 0; t < 4; ++t)                                  \
        af[t] = *(const bf16x8*)&As[P][(wm + t * 16 + l16) * 32 + ((quad ^ sw) * 8)]; \
    _Pragma("unroll") for (int t = 0; t < 4; ++t)                                  \
        bfr[t] = *(const bf16x8*)&Bs[P][(wn + t * 16 + l16) * 32 + ((quad ^ sw) * 8)]; \
    _Pragma("unroll") for (int i = 0; i < 4; ++i)                                  \
        _Pragma("unroll") for (int j = 0; j < 4; ++j)                              \
            acc[i][j] = __builtin_amdgcn_mfma_f32_16x16x32_bf16(af[i], bfr[j],     \
                                                                acc[i][j], 0, 0, 0); \
  } while (0)

  // prologue: stage 0 fully resident in buf 0
  ALOAD(0); ISSUEW(0, 0);
  WAITVM(0);
  AWRITE(0);
  WAITLG(); BAR();

  // stages 0..29, two per iteration (P literal)
  for (int k = 0; k < 30; k += 2) {
    ALOAD((k + 1) * 32); ISSUEW((k + 1) * 32, 1);
    QKV_COMPUTE(0);
    WAITVM(0); AWRITE(1); WAITLG(); BAR();

    ALOAD((k + 2) * 32); ISSUEW((k + 2) * 32, 0);
    QKV_COMPUTE(1);
    WAITVM(0); AWRITE(0); WAITLG(); BAR();
  }
  // stage 30 (buf 0) while staging 31 (buf 1)
  ALOAD(31 * 32); ISSUEW(31 * 32, 1);
  QKV_COMPUTE(0);
  WAITVM(0); AWRITE(1); WAITLG(); BAR();
  // stage 31
  QKV_COMPUTE(1);

#pragma unroll
  for (int i = 0; i < 4; ++i) {
#pragma unroll
    for (int j = 0; j < 4; ++j) {
      const int col = bn * 128 + wn + j * 16 + l16;
      const float bv = bias[col];
#pragma unroll
      for (int r = 0; r < 4; ++r) {
        const int row = bm * 128 + wm + i * 16 + quad * 4 + r;
        const float val = (acc[i][j][r] + bv) * oscale;
        const int b = row >> 11, s = row & (SEQ - 1);
        const int h = col >> 6, d = col & (DH - 1);
        size_t idx;
        if (mode == 0) idx = ((size_t)(b * HEADS + h) * SEQ + s) * DH + d;
        else           idx = ((size_t)(b * HEADS + h) * DH + d) * SEQ + s;
        O[idx] = f2bf(val);
      }
    }
  }
#undef ALOAD
#undef ISSUEW
#undef AWRITE
#undef QKV_COMPUTE
}

// ---------------- output projection: 128x128 tile (round-7 verified, verbatim) ----
__global__ void __launch_bounds__(256) out_gemm(const unsigned short* __restrict__ AO,
                                                const unsigned short* __restrict__ Wob,
                                                const float* __restrict__ bo,
                                                float* __restrict__ out) {
  __shared__ unsigned short As[3][128 * 32];
  __shared__ unsigned short Bs[3][128 * 32];
  const int bid = blockIdx.x, bm = bid & 31, bn = bid >> 5;
  const int tid = threadIdx.x, lane = tid & 63, wave = tid >> 6;
  const int l16 = lane & 15, quad = lane >> 4;
  const int wm = (wave >> 1) * 64, wn = (wave & 1) * 64;
  const int sw = (l16 >> 1) & 3;
  f32x4 acc[4][4] = {};

  const int r0 = tid >> 2, p0 = tid & 3;
  const int c0 = (p0 ^ ((r0 >> 1) & 3)) * 8;
  const int r1 = (256 + tid) >> 2;
  const int c1 = (p0 ^ ((r1 >> 1) & 3)) * 8;
  const unsigned short* Arow0 = AO + (size_t)(bm * 128 + r0) * KDIM + c0;
  const unsigned short* Arow1 = AO + (size_t)(bm * 128 + r1) * KDIM + c1;
  const unsigned short* Wrow0 = Wob + (size_t)(bn * 128 + r0) * KDIM + c0;
  const unsigned short* Wrow1 = Wob + (size_t)(bn * 128 + r1) * KDIM + c1;

#define OUT_ISSUE(K0, P)                                    \
  do {                                                      \
    cp16(Arow0 + (K0), &As[P][tid * 8]);                    \
    cp16(Arow1 + (K0), &As[P][(256 + tid) * 8]);            \
    cp16(Wrow0 + (K0), &Bs[P][tid * 8]);                    \
    cp16(Wrow1 + (K0), &Bs[P][(256 + tid) * 8]);            \
  } while (0)

#define OUT_COMPUTE(P)                                                             \
  do {                                                                             \
    bf16x8 af[4], bfr[4];                                                          \
    _Pragma("unroll") for (int t = 0; t < 4; ++t)                                  \
        af[t] = *(const bf16x8*)&As[P][(wm + t * 16 + l16) * 32 + ((quad ^ sw) * 8)]; \
    _Pragma("unroll") for (int t = 0; t < 4; ++t)                                  \
        bfr[t] = *(const bf16x8*)&Bs[P][(wn + t * 16 + l16) * 32 + ((quad ^ sw) * 8)]; \
    _Pragma("unroll") for (int i = 0; i < 4; ++i)                                  \
        _Pragma("unroll") for (int j = 0; j < 4; ++j)                              \
            acc[i][j] = __builtin_amdgcn_mfma_f32_16x16x32_bf16(af[i], bfr[j],     \
                                                                acc[i][j], 0, 0, 0); \
  } while (0)

  OUT_ISSUE(0, 0);
  OUT_ISSUE(32, 1);
  for (int k = 0; k < 30; k += 3) {
    BAR(); OUT_ISSUE((k + 2) * 32, 2); WAITVM(8); BAR(); OUT_COMPUTE(0);
    BAR(); OUT_ISSUE((k + 3) * 32, 0); WAITVM(8); BAR(); OUT_COMPUTE(1);
    BAR(); OUT_ISSUE((k + 4) * 32, 1); WAITVM(8); BAR(); OUT_COMPUTE(2);
  }
  WAITVM(4); BAR(); OUT_COMPUTE(0);   // stage 30
  WAITVM(0); BAR(); OUT_COMPUTE(1);   // stage 31

#pragma unroll
  for (int i = 0; i < 4; ++i)
#pragma unroll
    for (int j = 0; j < 4; ++j) {
      const int col = bn * 128 + wn + j * 16 + l16;
      const float bv = bo[col];
#pragma unroll
      for (int r = 0; r < 4; ++r) {
        const int row = bm * 128 + wm + i * 16 + quad * 4 + r;
        out[(size_t)row * D_MODEL + col] = acc[i][j][r] + bv;
      }
    }
#undef OUT_ISSUE
#undef OUT_COMPUTE
}

// ---------------- flash attention (round-4 VERIFIED kernel, verbatim) -------------
__global__ void __launch_bounds__(256, 1) attn(const unsigned short* __restrict__ Qh,
                                               const unsigned short* __restrict__ Kh,
                                               const unsigned short* __restrict__ Vt,
                                               unsigned short* __restrict__ AO) {
  __shared__ __align__(16) char smem[65536];
  // stage p: Ks = smem + p*32768          [128 key][64 dh], XOR-swizzled
  //          Vs = smem + p*32768 + 16384  [64 d][128 key],  XOR-swizzled

  const int bid = blockIdx.x;
  const int qt = bid >> 5, head = bid & 31, b = head >> 4, h = head & 15;
  const int tid = threadIdx.x;
  const int lane = tid & 63, wave = tid >> 6;
  const int wq = wave >> 1, wk = wave & 1;
  const int l31 = lane & 31, hh = lane >> 5;

  const unsigned short* Qhead = Qh + (size_t)(b * HEADS + h) * SEQ * DH;
  const unsigned short* Khead = Kh + (size_t)(b * HEADS + h) * SEQ * DH;
  const unsigned short* Vhead = Vt + (size_t)(b * HEADS + h) * DH * SEQ;

  const int qrow0 = qt * 128 + wq * 64 + l31;   // q-set 0; q-set 1 = +32
  bf16x8 aq0[4], aq1[4];
#pragma unroll
  for (int it = 0; it < 4; ++it) {
    aq0[it] = *(const bf16x8*)&Qhead[(size_t)qrow0 * DH + it * 16 + hh * 8];
    aq1[it] = *(const bf16x8*)&Qhead[(size_t)(qrow0 + 32) * DH + it * 16 + hh * 8];
  }

  f32x16 oacc0[2] = {}, oacc1[2] = {};
  float lsum0 = 0.f, lsum1 = 0.f;

#define ATT_STAGE(KC, P)                                                      \
  do {                                                                        \
    unsigned short* Ksp = (unsigned short*)(smem + (P) * 32768);              \
    unsigned short* Vsp = (unsigned short*)(smem + (P) * 32768 + 16384);      \
    _Pragma("unroll") for (int c = 0; c < 4; ++c) {                           \
      int s = c * 256 + tid;                                                  \
      int row = s >> 3, pblk = s & 7;                                         \
      int jb = pblk ^ (row & 7);                                              \
      cp16(Khead + (size_t)((KC) * 128 + row) * DH + jb * 8, &Ksp[s * 8]);    \
    }                                                                         \
    _Pragma("unroll") for (int c = 0; c < 4; ++c) {                           \
      int s = c * 256 + tid;                                                  \
      int d = s >> 4, pblk = s & 15;                                          \
      int jb = pblk ^ (d & 7);                                                \
      cp16(Vhead + (size_t)d * SEQ + (KC) * 128 + jb * 8, &Vsp[s * 8]);       \
    }                                                                         \
  } while (0)

#define ATT_SOFTMAX(SA, PB, LSUM)                                             \
  do {                                                                        \
    float p[16];                                                              \
    _Pragma("unroll") for (int r = 0; r < 16; ++r) {                          \
      p[r] = __builtin_amdgcn_exp2f((SA)[r]);                                 \
      (LSUM) += p[r];                                                         \
    }                                                                         \
    _Pragma("unroll") for (int c = 0; c < 2; ++c) {                           \
      unsigned x0 = pkbf(p[8 * c + 0], p[8 * c + 1]);                         \
      unsigned x1 = pkbf(p[8 * c + 2], p[8 * c + 3]);                         \
      unsigned y0 = pkbf(p[8 * c + 4], p[8 * c + 5]);                         \
      unsigned y1 = pkbf(p[8 * c + 6], p[8 * c + 7]);                         \
      asm("v_permlane32_swap_b32 %0, %1" : "+v"(x0), "+v"(y0));               \
      asm("v_permlane32_swap_b32 %0, %1" : "+v"(x1), "+v"(y1));               \
      union { unsigned u[4]; bf16x8 s; } pbu;                                 \
      pbu.u[0] = x0; pbu.u[1] = x1; pbu.u[2] = y0; pbu.u[3] = y1;             \
      (PB)[c] = pbu.s;                                                        \
    }                                                                         \
  } while (0)

#define ATT_COMPUTE(P)                                                        \
  do {                                                                        \
    const unsigned short* Ksp = (const unsigned short*)(smem + (P) * 32768);  \
    const unsigned short* Vsp =                                               \
        (const unsigned short*)(smem + (P) * 32768 + 16384);                  \
    __builtin_amdgcn_s_setprio(1);                                            \
    _Pragma("unroll") for (int sub = 0; sub < 2; ++sub) {                     \
      const int key = sub * 64 + wk * 32 + l31;                               \
      bf16x8 ak[4];                                                           \
      _Pragma("unroll") for (int it = 0; it < 4; ++it) {                      \
        const int sblk = (2 * it + hh) ^ (key & 7);                           \
        ak[it] = *(const bf16x8*)&Ksp[key * 64 + sblk * 8];                   \
      }                                                                       \
      bf16x8 pb0[2], pb1[2];                                                  \
      {                                                                       \
        f32x16 sa = {};                                                       \
        _Pragma("unroll") for (int it = 0; it < 4; ++it)                      \
          sa = __builtin_amdgcn_mfma_f32_32x32x16_bf16(ak[it], aq0[it], sa,   \
                                                       0, 0, 0);              \
        ATT_SOFTMAX(sa, pb0, lsum0);                                          \
      }                                                                       \
      {                                                                       \
        f32x16 sa = {};                                                       \
        _Pragma("unroll") for (int it = 0; it < 4; ++it)                      \
          sa = __builtin_amdgcn_mfma_f32_32x32x16_bf16(ak[it], aq1[it], sa,   \
                                                       0, 0, 0);              \
        ATT_SOFTMAX(sa, pb1, lsum1);                                          \
      }                                                                       \
      _Pragma("unroll") for (int c = 0; c < 2; ++c) {                         \
        const int K8 = sub * 8 + wk * 4 + 2 * c + hh;                         \
        _Pragma("unroll") for (int dh2 = 0; dh2 < 2; ++dh2) {                 \
          const int d = dh2 * 32 + l31;                                       \
          const int sv = K8 ^ (d & 7);                                        \
          bf16x8 av = *(const bf16x8*)&Vsp[d * 128 + sv * 8];                 \
          oacc0[dh2] = __builtin_amdgcn_mfma_f32_32x32x16_bf16(av, pb0[c],    \
                                                               oacc0[dh2],   \
                                                               0, 0, 0);     \
          oacc1[dh2] = __builtin_amdgcn_mfma_f32_32x32x16_bf16(av, pb1[c],    \
                                                               oacc1[dh2],   \
                                                               0, 0, 0);     \
        }                                                                     \
      }                                                                       \
    }                                                                         \
    __builtin_amdgcn_s_setprio(0);                                            \
  } while (0)

  ATT_STAGE(0, 0);
  for (int kc = 0; kc < 16; ++kc) {
    WAITVM(0);                          // tile kc's loads (and ANY stray vmem) done
    BAR();                              // all waves' stage-kc data visible
    if (kc < 15) ATT_STAGE(kc + 1, (kc + 1) & 1);  // next tile flies during compute
    ATT_COMPUTE(kc & 1);
    BAR();                              // all waves done reading buf kc&1
  }

  lsum0 += __shfl_xor(lsum0, 32);
  lsum1 += __shfl_xor(lsum1, 32);

  // epilogue scratch overlays stage 0 (last read at kc=14; final BAR passed)
  float* epiF = (float*)smem;                            // [2 wq][2048]
  float* lbuf = (float*)(smem + 16384);                  // [4][32]
  unsigned short* Oq = (unsigned short*)(smem + 17408);  // [2 wq][32 q][68]

#define ATT_EPI(OACC, LSUM, SET)                                              \
  do {                                                                        \
    if (lane < 32) lbuf[wave * 32 + l31] = (LSUM);                            \
    if (wk == 1) {                                                            \
      _Pragma("unroll") for (int dh2 = 0; dh2 < 2; ++dh2)                     \
        _Pragma("unroll") for (int r = 0; r < 16; ++r) {                      \
          const int d = dh2 * 32 + (r & 3) + 8 * (r >> 2) + 4 * hh;           \
          epiF[wq * 2048 + d * 32 + l31] = (OACC)[dh2][r];                    \
        }                                                                     \
    }                                                                         \
    __syncthreads();                                                          \
    if (wk == 0) {                                                            \
      const float linv = 1.0f / ((LSUM) + lbuf[(wq * 2 + 1) * 32 + l31]);     \
      _Pragma("unroll") for (int dh2 = 0; dh2 < 2; ++dh2) {                   \
        _Pragma("unroll") for (int r = 0; r < 16; r += 2) {                   \
          const int d = dh2 * 32 + (r & 3) + 8 * (r >> 2) + 4 * hh;           \
          const float v0 =                                                    \
              ((OACC)[dh2][r] + epiF[wq * 2048 + d * 32 + l31]) * linv;       \
          const float v1 =                                                    \
              ((OACC)[dh2][r + 1] + epiF[wq * 2048 + (d + 1) * 32 + l31]) *   \
              linv;                                                           \
          *(unsigned*)&Oq[wq * 2176 + l31 * 68 + d] = pkbf(v0, v1);           \
        }                                                                     \
      }                                                                       \
    }                                                                         \
    __syncthreads();                                                          \
    {                                                                         \
      const int qloc = tid >> 2, d0 = (tid & 3) * 16;                         \
      const int base = (qloc >> 5) * 2176 + (qloc & 31) * 68 + d0;            \
      unsigned u[8];                                                          \
      _Pragma("unroll") for (int i = 0; i < 8; ++i)                           \
        u[i] = *(const unsigned*)&Oq[base + i * 2];                           \
      const int row = qt * 128 + (qloc >> 5) * 64 + (SET) * 32 + (qloc & 31); \
      unsigned short* dst =                                                   \
          AO + ((size_t)(b * SEQ + row)) * D_MODEL + h * 64 + d0;             \
      *(uint4*)dst       = make_uint4(u[0], u[1], u[2], u[3]);                \
      *(uint4*)(dst + 8) = make_uint4(u[4], u[5], u[6], u[7]);                \
    }                                                                         \
  } while (0)

  ATT_EPI(oacc0, lsum0, 0);
  __syncthreads();
  ATT_EPI(oacc1, lsum1, 1);

#undef ATT_STAGE
#undef ATT_SOFTMAX
#undef ATT_COMPUTE
#undef ATT_EPI
}

extern "C" void kernel_launch(void* const* d_in, const int* in_sizes, int n_in,
                              void* d_out, int out_size, void* d_ws, size_t ws_size,
                              hipStream_t stream) {
  const float* q  = (const float*)d_in[0];
  const float* k  = (const float*)d_in[1];
  const float* v  = (const float*)d_in[2];
  const float* Wq = (const float*)d_in[3];
  const float* bq = (const float*)d_in[4];
  const float* Wk = (const float*)d_in[5];
  const float* bk = (const float*)d_in[6];
  const float* Wv = (const float*)d_in[7];
  const float* bv = (const float*)d_in[8];
  const float* Wo = (const float*)d_in[9];
  const float* bo = (const float*)d_in[10];
  float* out = (float*)d_out;

  char* ws = (char*)d_ws;
  const size_t MB = 1ull << 20;
  unsigned short* Wqb = (unsigned short*)(ws + 24 * MB);
  unsigned short* Wkb = (unsigned short*)(ws + 26 * MB);
  unsigned short* Wvb = (unsigned short*)(ws + 28 * MB);
  unsigned short* Wob = (unsigned short*)(ws + 30 * MB);
  unsigned short* Qh  = (unsigned short*)(ws + 32 * MB);
  unsigned short* Kh  = (unsigned short*)(ws + 40 * MB);
  unsigned short* Vt  = (unsigned short*)(ws + 48 * MB);
  unsigned short* AO  = (unsigned short*)(ws + 56 * MB);

  castall<<<4096, 256, 0, stream>>>(Wq, Wk, Wv, Wo, Wqb, Wkb, Wvb, Wob);

  const float qscale = 0.125f * 1.44269504088896f;  // fold 1/sqrt(Dh) and log2(e) into Q
  qkv_gemm<<<768, 256, 0, stream>>>(q, k, v, Wqb, Wkb, Wvb, bq, bk, bv,
                                    Qh, Kh, Vt, qscale);

  attn<<<512, 256, 0, stream>>>(Qh, Kh, Vt, AO);

  out_gemm<<<256, 256, 0, stream>>>(AO, Wob, bo, out);
}